// Round 1
// baseline (197.836 us; speedup 1.0000x reference)
//
#include <hip/hip_runtime.h>
#include <hip/hip_bf16.h>
#include <stdint.h>

typedef __bf16 bf16_t;
typedef bf16_t bf16x8 __attribute__((ext_vector_type(8)));
typedef bf16_t bf16x4 __attribute__((ext_vector_type(4)));
typedef float  f32x4  __attribute__((ext_vector_type(4)));

#define E_DIM 1024
#define B_ROWS 16384

__device__ __forceinline__ void gload_lds16(const void* g, void* l) {
    __builtin_amdgcn_global_load_lds(
        (const __attribute__((address_space(1))) void*)g,
        (__attribute__((address_space(3))) void*)l,
        16, 0, 0);
}

// ---------------------------------------------------------------------------
// f32 -> bf16 flat convert (for Wo)
// ---------------------------------------------------------------------------
__global__ void cvt_f32_bf16_k(const float* __restrict__ in, bf16_t* __restrict__ out, int n4) {
    int i = blockIdx.x * blockDim.x + threadIdx.x;
    if (i < n4) {
        f32x4 v = ((const f32x4*)in)[i];
        bf16x4 o;
        o[0] = (bf16_t)v[0]; o[1] = (bf16_t)v[1];
        o[2] = (bf16_t)v[2]; o[3] = (bf16_t)v[3];
        ((bf16x4*)out)[i] = o;
    }
}

// ---------------------------------------------------------------------------
// transposed f32 -> bf16 convert: out[k][j] = in[j][k]  (1024x1024) (for Wv)
// ---------------------------------------------------------------------------
__global__ __launch_bounds__(256) void transpose_cvt_k(const float* __restrict__ in,
                                                       bf16_t* __restrict__ out) {
    __shared__ float t[64][65];
    int bx = blockIdx.x & 15;   // k tile
    int by = blockIdx.x >> 4;   // j tile
    int j0 = by * 64, k0 = bx * 64;
    int tid = threadIdx.x;
#pragma unroll
    for (int p = 0; p < 4; ++p) {
        int u = tid + 256 * p;
        int r = u >> 4, c4 = u & 15;
        f32x4 v = *(const f32x4*)(in + (size_t)(j0 + r) * E_DIM + k0 + c4 * 4);
        t[r][c4 * 4 + 0] = v[0]; t[r][c4 * 4 + 1] = v[1];
        t[r][c4 * 4 + 2] = v[2]; t[r][c4 * 4 + 3] = v[3];
    }
    __syncthreads();
#pragma unroll
    for (int p = 0; p < 4; ++p) {
        int u = tid + 256 * p;
        int r = u >> 4, c4 = u & 15;
        bf16x4 o;
        o[0] = (bf16_t)t[c4 * 4 + 0][r];
        o[1] = (bf16_t)t[c4 * 4 + 1][r];
        o[2] = (bf16_t)t[c4 * 4 + 2][r];
        o[3] = (bf16_t)t[c4 * 4 + 3][r];
        *(bf16x4*)(out + (size_t)(k0 + r) * E_DIM + j0 + c4 * 4) = o;
    }
}

// ---------------------------------------------------------------------------
// b_eff[i] = sum_j Wo[i][j] * bv[j] + bo[i]
// ---------------------------------------------------------------------------
__global__ void fuse_bias_k(const float* __restrict__ Wo, const float* __restrict__ bqkv,
                            const float* __restrict__ bo, float* __restrict__ beff) {
    const float* bv = bqkv + 2 * E_DIM;
    int i = blockIdx.x;
    float s = 0.f;
    for (int j = threadIdx.x; j < E_DIM; j += 64)
        s += Wo[(size_t)i * E_DIM + j] * bv[j];
#pragma unroll
    for (int o = 32; o > 0; o >>= 1) s += __shfl_down(s, o);
    if (threadIdx.x == 0) beff[i] = s + bo[i];
}

// ---------------------------------------------------------------------------
// Fusion GEMM: Weff[i][k] = sum_j WoB[i][j] * WvT[k][j]   (NT, bf16 MFMA)
// 128x128 tile, BK=64, 4 waves. grid = 128 (2 matrices x 64 tiles)
// ---------------------------------------------------------------------------
__global__ __launch_bounds__(256, 2) void fuse_gemm_k(const bf16_t* __restrict__ WoB,
                                                      const bf16_t* __restrict__ WvT,
                                                      bf16_t* __restrict__ Weff) {
    const size_t MAT = (size_t)E_DIM * E_DIM;
    int bid = blockIdx.x;
    int ms = bid >> 6;
    int t  = bid & 63;
    int mt = t >> 3, nt = t & 7;
    const bf16_t* A  = WoB + (size_t)ms * MAT;
    const bf16_t* Bm = WvT + (size_t)ms * MAT;
    bf16_t*       C  = Weff + (size_t)ms * MAT;
    int m0 = mt * 128, n0 = nt * 128;

    __shared__ __align__(16) bf16_t As[128][64];
    __shared__ __align__(16) bf16_t Bs[128][64];

    int tid = threadIdx.x;
    int lane = tid & 63;
    int wid = tid >> 6;
    int wrow = (wid >> 1) * 64;
    int wcol = (wid & 1) * 64;
    int cl = lane & 15;
    int rg = lane >> 4;

    f32x4 acc[4][4] = {};

    for (int kt = 0; kt < 16; ++kt) {
#pragma unroll
        for (int i = 0; i < 4; ++i) {
            int chunk = i * 256 + wid * 64 + lane;
            int row = chunk >> 3;
            int kk8 = (chunk & 7) * 8;
            char* la = (char*)(&As[0][0]) + (size_t)(i * 256 + wid * 64) * 16;
            char* lb = (char*)(&Bs[0][0]) + (size_t)(i * 256 + wid * 64) * 16;
            gload_lds16(A  + (size_t)(m0 + row) * E_DIM + kt * 64 + kk8, la);
            gload_lds16(Bm + (size_t)(n0 + row) * E_DIM + kt * 64 + kk8, lb);
        }
        __syncthreads();
#pragma unroll
        for (int ks = 0; ks < 2; ++ks) {
            int kk = ks * 32 + rg * 8;
            bf16x8 af[4], bq[4];
#pragma unroll
            for (int m = 0; m < 4; ++m) af[m] = *(const bf16x8*)(&As[wrow + m * 16 + cl][kk]);
#pragma unroll
            for (int n = 0; n < 4; ++n) bq[n] = *(const bf16x8*)(&Bs[wcol + n * 16 + cl][kk]);
#pragma unroll
            for (int m = 0; m < 4; ++m)
#pragma unroll
                for (int n = 0; n < 4; ++n)
                    acc[m][n] = __builtin_amdgcn_mfma_f32_16x16x32_bf16(af[m], bq[n], acc[m][n], 0, 0, 0);
        }
        __syncthreads();
    }

#pragma unroll
    for (int m = 0; m < 4; ++m) {
        int r = m0 + wrow + m * 16 + rg * 4;
#pragma unroll
        for (int n = 0; n < 4; ++n) {
            int c = n0 + wcol + n * 16 + cl;
#pragma unroll
            for (int j = 0; j < 4; ++j)
                C[(size_t)(r + j) * E_DIM + c] = (bf16_t)acc[m][n][j];
        }
    }
}

// ---------------------------------------------------------------------------
// Main GEMM: out[b][sel*1024 + n] = sum_k X[b][k] * Weff[sel][n][k] + beff[sel][n]
// X = ecg (sel 0) / text (sel 1), f32, reg-staged -> bf16 LDS.
// 128x128 tile, BK=64, 4 waves, grid = 2048, XCD-swizzled, mt-major chunks.
// ---------------------------------------------------------------------------
__global__ __launch_bounds__(256, 2) void main_gemm_k(const float* __restrict__ text,
                                                      const float* __restrict__ ecg,
                                                      const bf16_t* __restrict__ Weff,
                                                      const float* __restrict__ beff,
                                                      float* __restrict__ out) {
    int bid = blockIdx.x;
    // bijective XCD swizzle: nwg = 2048, 2048 % 8 == 0
    int wg = (bid & 7) * 256 + (bid >> 3);
    int nt = wg & 15;   // 16 col tiles (8 per matrix)
    int mt = wg >> 4;   // 128 row tiles
    int sel = nt >> 3;
    const float*  A = sel ? text : ecg;
    const bf16_t* W = Weff + (size_t)sel * E_DIM * E_DIM;
    const float* bb = beff + sel * E_DIM;
    int n0 = (nt & 7) * 128;
    int m0 = mt * 128;

    __shared__ __align__(16) bf16_t As[128][64];
    __shared__ __align__(16) bf16_t Bs[128][64];

    int tid = threadIdx.x;
    int lane = tid & 63;
    int wid = tid >> 6;
    int wrow = (wid >> 1) * 64;
    int wcol = (wid & 1) * 64;
    int cl = lane & 15;
    int rg = lane >> 4;

    f32x4 acc[4][4] = {};

    for (int kt = 0; kt < 16; ++kt) {
        // B tile via async global->LDS (16B/lane)
#pragma unroll
        for (int i = 0; i < 4; ++i) {
            int chunk = i * 256 + wid * 64 + lane;
            int brow = chunk >> 3;
            int bk = (chunk & 7) * 8;
            char* lb = (char*)(&Bs[0][0]) + (size_t)(i * 256 + wid * 64) * 16;
            gload_lds16(W + (size_t)(n0 + brow) * E_DIM + kt * 64 + bk, lb);
        }
        // A tile: f32 global -> regs -> bf16 -> LDS
#pragma unroll
        for (int i = 0; i < 4; ++i) {
            int u = i * 256 + tid;
            int arow = u >> 3;
            int akc = u & 7;
            const f32x4* ga = (const f32x4*)(A + (size_t)(m0 + arow) * E_DIM + kt * 64 + akc * 8);
            f32x4 lo = ga[0];
            f32x4 hi = ga[1];
            bf16x8 v;
            v[0] = (bf16_t)lo[0]; v[1] = (bf16_t)lo[1]; v[2] = (bf16_t)lo[2]; v[3] = (bf16_t)lo[3];
            v[4] = (bf16_t)hi[0]; v[5] = (bf16_t)hi[1]; v[6] = (bf16_t)hi[2]; v[7] = (bf16_t)hi[3];
            *(bf16x8*)(&As[arow][akc * 8]) = v;
        }
        __syncthreads();
#pragma unroll
        for (int ks = 0; ks < 2; ++ks) {
            int kk = ks * 32 + rg * 8;
            bf16x8 af[4], bq[4];
#pragma unroll
            for (int m = 0; m < 4; ++m) af[m] = *(const bf16x8*)(&As[wrow + m * 16 + cl][kk]);
#pragma unroll
            for (int n = 0; n < 4; ++n) bq[n] = *(const bf16x8*)(&Bs[wcol + n * 16 + cl][kk]);
#pragma unroll
            for (int m = 0; m < 4; ++m)
#pragma unroll
                for (int n = 0; n < 4; ++n)
                    acc[m][n] = __builtin_amdgcn_mfma_f32_16x16x32_bf16(af[m], bq[n], acc[m][n], 0, 0, 0);
        }
        __syncthreads();
    }

    // epilogue: +bias, f32 store (out width = 2048)
#pragma unroll
    for (int n = 0; n < 4; ++n) {
        int ch = n0 + wcol + n * 16 + cl;
        float bias = bb[ch];
        size_t gc = (size_t)sel * E_DIM + ch;
#pragma unroll
        for (int m = 0; m < 4; ++m) {
            int r = m0 + wrow + m * 16 + rg * 4;
#pragma unroll
            for (int j = 0; j < 4; ++j)
                out[(size_t)(r + j) * (2 * E_DIM) + gc] = acc[m][n][j] + bias;
        }
    }
}

// ---------------------------------------------------------------------------
extern "C" void kernel_launch(void* const* d_in, const int* in_sizes, int n_in,
                              void* d_out, int out_size, void* d_ws, size_t ws_size,
                              hipStream_t stream) {
    const float* text   = (const float*)d_in[0];
    const float* ecg    = (const float*)d_in[1];
    const float* Wqkv_a = (const float*)d_in[7];
    const float* bqkv_a = (const float*)d_in[8];
    const float* Wo_a   = (const float*)d_in[9];
    const float* bo_a   = (const float*)d_in[10];
    const float* Wqkv_b = (const float*)d_in[11];
    const float* bqkv_b = (const float*)d_in[12];
    const float* Wo_b   = (const float*)d_in[13];
    const float* bo_b   = (const float*)d_in[14];

    const size_t MAT = (size_t)E_DIM * E_DIM;
    bf16_t* WoB  = (bf16_t*)d_ws;            // 2 * 2MB
    bf16_t* WvT  = WoB + 2 * MAT;            // 2 * 2MB
    bf16_t* Weff = WvT + 2 * MAT;            // 2 * 2MB
    float*  beff = (float*)(Weff + 2 * MAT); // 2 * 4KB   (total ~12MB)

    int n4 = (int)(MAT / 4);
    cvt_f32_bf16_k<<<1024, 256, 0, stream>>>(Wo_a, WoB, n4);
    cvt_f32_bf16_k<<<1024, 256, 0, stream>>>(Wo_b, WoB + MAT, n4);
    transpose_cvt_k<<<256, 256, 0, stream>>>(Wqkv_a + 2 * MAT, WvT);
    transpose_cvt_k<<<256, 256, 0, stream>>>(Wqkv_b + 2 * MAT, WvT + MAT);
    fuse_gemm_k<<<128, 256, 0, stream>>>(WoB, WvT, Weff);
    fuse_bias_k<<<1024, 64, 0, stream>>>(Wo_a, bqkv_a, bo_a, beff);
    fuse_bias_k<<<1024, 64, 0, stream>>>(Wo_b, bqkv_b, bo_b, beff + E_DIM);
    main_gemm_k<<<2048, 256, 0, stream>>>(text, ecg, Weff, beff, (float*)d_out);
}

// Round 2
// 178.520 us; speedup vs baseline: 1.1082x; 1.1082x over previous
//
#include <hip/hip_runtime.h>
#include <hip/hip_bf16.h>
#include <stdint.h>

typedef __bf16 bf16_t;
typedef bf16_t bf16x8 __attribute__((ext_vector_type(8)));
typedef bf16_t bf16x4 __attribute__((ext_vector_type(4)));
typedef float  f32x4  __attribute__((ext_vector_type(4)));

#define E_DIM 1024
#define B_ROWS 16384

__device__ __forceinline__ void gload_lds16(const void* g, void* l) {
    __builtin_amdgcn_global_load_lds(
        (const __attribute__((address_space(1))) void*)g,
        (__attribute__((address_space(3))) void*)l,
        16, 0, 0);
}

// ---------------------------------------------------------------------------
// f32 -> bf16 flat convert (for Wo)
// ---------------------------------------------------------------------------
__global__ void cvt_f32_bf16_k(const float* __restrict__ in, bf16_t* __restrict__ out, int n4) {
    int i = blockIdx.x * blockDim.x + threadIdx.x;
    if (i < n4) {
        f32x4 v = ((const f32x4*)in)[i];
        bf16x4 o;
        o[0] = (bf16_t)v[0]; o[1] = (bf16_t)v[1];
        o[2] = (bf16_t)v[2]; o[3] = (bf16_t)v[3];
        ((bf16x4*)out)[i] = o;
    }
}

// ---------------------------------------------------------------------------
// big f32 -> bf16 convert, grid-stride, 16B loads / 16B stores per thread
// ---------------------------------------------------------------------------
__global__ __launch_bounds__(256) void cvt_x_k(const float* __restrict__ in,
                                               bf16_t* __restrict__ out, int n8) {
    int stride = gridDim.x * blockDim.x;
    for (int i = blockIdx.x * blockDim.x + threadIdx.x; i < n8; i += stride) {
        f32x4 lo = ((const f32x4*)in)[2 * i];
        f32x4 hi = ((const f32x4*)in)[2 * i + 1];
        bf16x8 v;
        v[0] = (bf16_t)lo[0]; v[1] = (bf16_t)lo[1]; v[2] = (bf16_t)lo[2]; v[3] = (bf16_t)lo[3];
        v[4] = (bf16_t)hi[0]; v[5] = (bf16_t)hi[1]; v[6] = (bf16_t)hi[2]; v[7] = (bf16_t)hi[3];
        ((bf16x8*)out)[i] = v;
    }
}

// ---------------------------------------------------------------------------
// transposed f32 -> bf16 convert: out[k][j] = in[j][k]  (1024x1024) (for Wv)
// ---------------------------------------------------------------------------
__global__ __launch_bounds__(256) void transpose_cvt_k(const float* __restrict__ in,
                                                       bf16_t* __restrict__ out) {
    __shared__ float t[64][65];
    int bx = blockIdx.x & 15;   // k tile
    int by = blockIdx.x >> 4;   // j tile
    int j0 = by * 64, k0 = bx * 64;
    int tid = threadIdx.x;
#pragma unroll
    for (int p = 0; p < 4; ++p) {
        int u = tid + 256 * p;
        int r = u >> 4, c4 = u & 15;
        f32x4 v = *(const f32x4*)(in + (size_t)(j0 + r) * E_DIM + k0 + c4 * 4);
        t[r][c4 * 4 + 0] = v[0]; t[r][c4 * 4 + 1] = v[1];
        t[r][c4 * 4 + 2] = v[2]; t[r][c4 * 4 + 3] = v[3];
    }
    __syncthreads();
#pragma unroll
    for (int p = 0; p < 4; ++p) {
        int u = tid + 256 * p;
        int r = u >> 4, c4 = u & 15;
        bf16x4 o;
        o[0] = (bf16_t)t[c4 * 4 + 0][r];
        o[1] = (bf16_t)t[c4 * 4 + 1][r];
        o[2] = (bf16_t)t[c4 * 4 + 2][r];
        o[3] = (bf16_t)t[c4 * 4 + 3][r];
        *(bf16x4*)(out + (size_t)(k0 + r) * E_DIM + j0 + c4 * 4) = o;
    }
}

// ---------------------------------------------------------------------------
// b_eff[i] = sum_j Wo[i][j] * bv[j] + bo[i]
// ---------------------------------------------------------------------------
__global__ void fuse_bias_k(const float* __restrict__ Wo, const float* __restrict__ bqkv,
                            const float* __restrict__ bo, float* __restrict__ beff) {
    const float* bv = bqkv + 2 * E_DIM;
    int i = blockIdx.x;
    float s = 0.f;
    for (int j = threadIdx.x; j < E_DIM; j += 64)
        s += Wo[(size_t)i * E_DIM + j] * bv[j];
#pragma unroll
    for (int o = 32; o > 0; o >>= 1) s += __shfl_down(s, o);
    if (threadIdx.x == 0) beff[i] = s + bo[i];
}

// ---------------------------------------------------------------------------
// Fusion GEMM: Weff[i][k] = sum_j WoB[i][j] * WvT[k][j]   (NT, bf16 MFMA)
// 128x128 tile, BK=64, 4 waves. grid = 128 (2 matrices x 64 tiles)
// ---------------------------------------------------------------------------
__global__ __launch_bounds__(256, 2) void fuse_gemm_k(const bf16_t* __restrict__ WoB,
                                                      const bf16_t* __restrict__ WvT,
                                                      bf16_t* __restrict__ Weff) {
    const size_t MAT = (size_t)E_DIM * E_DIM;
    int bid = blockIdx.x;
    int ms = bid >> 6;
    int t  = bid & 63;
    int mt = t >> 3, nt = t & 7;
    const bf16_t* A  = WoB + (size_t)ms * MAT;
    const bf16_t* Bm = WvT + (size_t)ms * MAT;
    bf16_t*       C  = Weff + (size_t)ms * MAT;
    int m0 = mt * 128, n0 = nt * 128;

    __shared__ __align__(16) bf16_t As[128][64];
    __shared__ __align__(16) bf16_t Bs[128][64];

    int tid = threadIdx.x;
    int lane = tid & 63;
    int wid = tid >> 6;
    int wrow = (wid >> 1) * 64;
    int wcol = (wid & 1) * 64;
    int cl = lane & 15;
    int rg = lane >> 4;

    f32x4 acc[4][4] = {};

    for (int kt = 0; kt < 16; ++kt) {
#pragma unroll
        for (int i = 0; i < 4; ++i) {
            int chunk = i * 256 + wid * 64 + lane;
            int row = chunk >> 3;
            int kk8 = (chunk & 7) * 8;
            char* la = (char*)(&As[0][0]) + (size_t)(i * 256 + wid * 64) * 16;
            char* lb = (char*)(&Bs[0][0]) + (size_t)(i * 256 + wid * 64) * 16;
            gload_lds16(A  + (size_t)(m0 + row) * E_DIM + kt * 64 + kk8, la);
            gload_lds16(Bm + (size_t)(n0 + row) * E_DIM + kt * 64 + kk8, lb);
        }
        __syncthreads();
#pragma unroll
        for (int ks = 0; ks < 2; ++ks) {
            int kk = ks * 32 + rg * 8;
            bf16x8 af[4], bq[4];
#pragma unroll
            for (int m = 0; m < 4; ++m) af[m] = *(const bf16x8*)(&As[wrow + m * 16 + cl][kk]);
#pragma unroll
            for (int n = 0; n < 4; ++n) bq[n] = *(const bf16x8*)(&Bs[wcol + n * 16 + cl][kk]);
#pragma unroll
            for (int m = 0; m < 4; ++m)
#pragma unroll
                for (int n = 0; n < 4; ++n)
                    acc[m][n] = __builtin_amdgcn_mfma_f32_16x16x32_bf16(af[m], bq[n], acc[m][n], 0, 0, 0);
        }
        __syncthreads();
    }

#pragma unroll
    for (int m = 0; m < 4; ++m) {
        int r = m0 + wrow + m * 16 + rg * 4;
#pragma unroll
        for (int n = 0; n < 4; ++n) {
            int c = n0 + wcol + n * 16 + cl;
#pragma unroll
            for (int j = 0; j < 4; ++j)
                C[(size_t)(r + j) * E_DIM + c] = (bf16_t)acc[m][n][j];
        }
    }
}

// ---------------------------------------------------------------------------
// FAST main GEMM: both operands bf16 via global_load_lds (m97 structure).
// out[b][sel*1024+n] = sum_k Xb[sel][b][k] * Weff[sel][n][k] + beff[sel][n]
// 128x128 tile, BK=64, 4 waves, grid = 2048, XCD-swizzled, mt-major chunks.
// ---------------------------------------------------------------------------
__global__ __launch_bounds__(256, 2) void main_gemm_bf16_k(const bf16_t* __restrict__ Xb,
                                                           const bf16_t* __restrict__ Weff,
                                                           const float* __restrict__ beff,
                                                           float* __restrict__ out) {
    int bid = blockIdx.x;
    // bijective XCD swizzle: nwg = 2048, 2048 % 8 == 0
    int wg = (bid & 7) * 256 + (bid >> 3);
    int nt = wg & 15;   // 16 col tiles (8 per matrix)
    int mt = wg >> 4;   // 128 row tiles
    int sel = nt >> 3;
    const bf16_t* A = Xb + (size_t)sel * B_ROWS * E_DIM;
    const bf16_t* W = Weff + (size_t)sel * E_DIM * E_DIM;
    const float* bb = beff + sel * E_DIM;
    int n0 = (nt & 7) * 128;
    int m0 = mt * 128;

    __shared__ __align__(16) bf16_t As[128][64];
    __shared__ __align__(16) bf16_t Bs[128][64];

    int tid = threadIdx.x;
    int lane = tid & 63;
    int wid = tid >> 6;
    int wrow = (wid >> 1) * 64;
    int wcol = (wid & 1) * 64;
    int cl = lane & 15;
    int rg = lane >> 4;

    f32x4 acc[4][4] = {};

    for (int kt = 0; kt < 16; ++kt) {
#pragma unroll
        for (int i = 0; i < 4; ++i) {
            int chunk = i * 256 + wid * 64 + lane;
            int row = chunk >> 3;
            int kk8 = (chunk & 7) * 8;
            char* la = (char*)(&As[0][0]) + (size_t)(i * 256 + wid * 64) * 16;
            char* lb = (char*)(&Bs[0][0]) + (size_t)(i * 256 + wid * 64) * 16;
            gload_lds16(A + (size_t)(m0 + row) * E_DIM + kt * 64 + kk8, la);
            gload_lds16(W + (size_t)(n0 + row) * E_DIM + kt * 64 + kk8, lb);
        }
        __syncthreads();
#pragma unroll
        for (int ks = 0; ks < 2; ++ks) {
            int kk = ks * 32 + rg * 8;
            bf16x8 af[4], bq[4];
#pragma unroll
            for (int m = 0; m < 4; ++m) af[m] = *(const bf16x8*)(&As[wrow + m * 16 + cl][kk]);
#pragma unroll
            for (int n = 0; n < 4; ++n) bq[n] = *(const bf16x8*)(&Bs[wcol + n * 16 + cl][kk]);
#pragma unroll
            for (int m = 0; m < 4; ++m)
#pragma unroll
                for (int n = 0; n < 4; ++n)
                    acc[m][n] = __builtin_amdgcn_mfma_f32_16x16x32_bf16(af[m], bq[n], acc[m][n], 0, 0, 0);
        }
        __syncthreads();
    }

    // epilogue: +bias, f32 store (out width = 2048)
#pragma unroll
    for (int n = 0; n < 4; ++n) {
        int ch = n0 + wcol + n * 16 + cl;
        float bias = bb[ch];
        size_t gc = (size_t)sel * E_DIM + ch;
#pragma unroll
        for (int m = 0; m < 4; ++m) {
            int r = m0 + wrow + m * 16 + rg * 4;
#pragma unroll
            for (int j = 0; j < 4; ++j)
                out[(size_t)(r + j) * (2 * E_DIM) + gc] = acc[m][n][j] + bias;
        }
    }
}

// ---------------------------------------------------------------------------
// FALLBACK main GEMM (f32 A reg-staged) — used if ws_size too small for Xb.
// ---------------------------------------------------------------------------
__global__ __launch_bounds__(256, 2) void main_gemm_k(const float* __restrict__ text,
                                                      const float* __restrict__ ecg,
                                                      const bf16_t* __restrict__ Weff,
                                                      const float* __restrict__ beff,
                                                      float* __restrict__ out) {
    int bid = blockIdx.x;
    int wg = (bid & 7) * 256 + (bid >> 3);
    int nt = wg & 15;
    int mt = wg >> 4;
    int sel = nt >> 3;
    const float*  A = sel ? text : ecg;
    const bf16_t* W = Weff + (size_t)sel * E_DIM * E_DIM;
    const float* bb = beff + sel * E_DIM;
    int n0 = (nt & 7) * 128;
    int m0 = mt * 128;

    __shared__ __align__(16) bf16_t As[128][64];
    __shared__ __align__(16) bf16_t Bs[128][64];

    int tid = threadIdx.x;
    int lane = tid & 63;
    int wid = tid >> 6;
    int wrow = (wid >> 1) * 64;
    int wcol = (wid & 1) * 64;
    int cl = lane & 15;
    int rg = lane >> 4;

    f32x4 acc[4][4] = {};

    for (int kt = 0; kt < 16; ++kt) {
#pragma unroll
        for (int i = 0; i < 4; ++i) {
            int chunk = i * 256 + wid * 64 + lane;
            int brow = chunk >> 3;
            int bk = (chunk & 7) * 8;
            char* lb = (char*)(&Bs[0][0]) + (size_t)(i * 256 + wid * 64) * 16;
            gload_lds16(W + (size_t)(n0 + brow) * E_DIM + kt * 64 + bk, lb);
        }
#pragma unroll
        for (int i = 0; i < 4; ++i) {
            int u = i * 256 + tid;
            int arow = u >> 3;
            int akc = u & 7;
            const f32x4* ga = (const f32x4*)(A + (size_t)(m0 + arow) * E_DIM + kt * 64 + akc * 8);
            f32x4 lo = ga[0];
            f32x4 hi = ga[1];
            bf16x8 v;
            v[0] = (bf16_t)lo[0]; v[1] = (bf16_t)lo[1]; v[2] = (bf16_t)lo[2]; v[3] = (bf16_t)lo[3];
            v[4] = (bf16_t)hi[0]; v[5] = (bf16_t)hi[1]; v[6] = (bf16_t)hi[2]; v[7] = (bf16_t)hi[3];
            *(bf16x8*)(&As[arow][akc * 8]) = v;
        }
        __syncthreads();
#pragma unroll
        for (int ks = 0; ks < 2; ++ks) {
            int kk = ks * 32 + rg * 8;
            bf16x8 af[4], bq[4];
#pragma unroll
            for (int m = 0; m < 4; ++m) af[m] = *(const bf16x8*)(&As[wrow + m * 16 + cl][kk]);
#pragma unroll
            for (int n = 0; n < 4; ++n) bq[n] = *(const bf16x8*)(&Bs[wcol + n * 16 + cl][kk]);
#pragma unroll
            for (int m = 0; m < 4; ++m)
#pragma unroll
                for (int n = 0; n < 4; ++n)
                    acc[m][n] = __builtin_amdgcn_mfma_f32_16x16x32_bf16(af[m], bq[n], acc[m][n], 0, 0, 0);
        }
        __syncthreads();
    }

#pragma unroll
    for (int n = 0; n < 4; ++n) {
        int ch = n0 + wcol + n * 16 + cl;
        float bias = bb[ch];
        size_t gc = (size_t)sel * E_DIM + ch;
#pragma unroll
        for (int m = 0; m < 4; ++m) {
            int r = m0 + wrow + m * 16 + rg * 4;
#pragma unroll
            for (int j = 0; j < 4; ++j)
                out[(size_t)(r + j) * (2 * E_DIM) + gc] = acc[m][n][j] + bias;
        }
    }
}

// ---------------------------------------------------------------------------
extern "C" void kernel_launch(void* const* d_in, const int* in_sizes, int n_in,
                              void* d_out, int out_size, void* d_ws, size_t ws_size,
                              hipStream_t stream) {
    const float* text   = (const float*)d_in[0];
    const float* ecg    = (const float*)d_in[1];
    const float* Wqkv_a = (const float*)d_in[7];
    const float* bqkv_a = (const float*)d_in[8];
    const float* Wo_a   = (const float*)d_in[9];
    const float* bo_a   = (const float*)d_in[10];
    const float* Wqkv_b = (const float*)d_in[11];
    const float* bqkv_b = (const float*)d_in[12];
    const float* Wo_b   = (const float*)d_in[13];
    const float* bo_b   = (const float*)d_in[14];

    const size_t MAT = (size_t)E_DIM * E_DIM;
    const size_t XMAT = (size_t)B_ROWS * E_DIM;
    bf16_t* WoB  = (bf16_t*)d_ws;            // 2 * 2MB
    bf16_t* WvT  = WoB + 2 * MAT;            // 2 * 2MB
    bf16_t* Weff = WvT + 2 * MAT;            // 2 * 2MB
    float*  beff = (float*)(Weff + 2 * MAT); // 2 * 4KB
    bf16_t* Xb   = (bf16_t*)(beff + 2 * E_DIM); // 2 * 32MB (fast path only)

    size_t need_fast = 12 * MAT * sizeof(bf16_t) + 2 * E_DIM * sizeof(float)
                     + 2 * XMAT * sizeof(bf16_t);
    bool fast = ws_size >= need_fast;

    int n4 = (int)(MAT / 4);
    cvt_f32_bf16_k<<<1024, 256, 0, stream>>>(Wo_a, WoB, n4);
    cvt_f32_bf16_k<<<1024, 256, 0, stream>>>(Wo_b, WoB + MAT, n4);
    transpose_cvt_k<<<256, 256, 0, stream>>>(Wqkv_a + 2 * MAT, WvT);
    transpose_cvt_k<<<256, 256, 0, stream>>>(Wqkv_b + 2 * MAT, WvT + MAT);
    fuse_gemm_k<<<128, 256, 0, stream>>>(WoB, WvT, Weff);
    fuse_bias_k<<<1024, 64, 0, stream>>>(Wo_a, bqkv_a, bo_a, beff);
    fuse_bias_k<<<1024, 64, 0, stream>>>(Wo_b, bqkv_b, bo_b, beff + E_DIM);

    if (fast) {
        int n8 = (int)(XMAT / 8);
        cvt_x_k<<<2048, 256, 0, stream>>>(ecg,  Xb,        n8);  // sel 0
        cvt_x_k<<<2048, 256, 0, stream>>>(text, Xb + XMAT, n8);  // sel 1
        main_gemm_bf16_k<<<2048, 256, 0, stream>>>(Xb, Weff, beff, (float*)d_out);
    } else {
        main_gemm_k<<<2048, 256, 0, stream>>>(text, ecg, Weff, beff, (float*)d_out);
    }
}